// Round 4
// baseline (3646.649 us; speedup 1.0000x reference)
//
#include <hip/hip_runtime.h>

#define NNODES 100000
#define NEDGES 300000
#define KF     1433
#define KP     1536   // 48*32, zero-padded tail
#define HID    16
#define NC     7
#define ROWS   4                 // rows per wave-group
#define NGRP   (NNODES / ROWS)   // 25000 groups, exact
#define NITK   45                // ceil(1433/32) k-iterations of 32

// ---------------------------------------------------------------------------
// Kernel A: y = x @ w1.  1024 threads (16 waves = 4 waves/SIMD, 1 block/CU by
// LDS 96KB).  Half-wave j-split: lane = 32*h + m; half h owns 8 of 16 output
// cols, lanes in a half split K with stride 32.  acc[4][8] = 32 VGPR -> total
// ~55 VGPR, fits the empirical 64-VGPR cap for 1024-thread blocks (rounds 2/3
// proved the cap is 64 regardless of __launch_bounds__ min-waves; acc[4][16]
// spilled -> 5.2 GB scratch fetch).  Depth-2 register prefetch on x.
// W1^T staged fp32 in LDS; the two halves' LDS reads are 2-way bank aliased
// (free).  x loads: 128B per half, duplicate addrs across halves coalesce.
// ---------------------------------------------------------------------------
__global__ __launch_bounds__(1024, 4) void gemm_xw1(const float* __restrict__ x,
                                                    const float* __restrict__ w1,
                                                    float* __restrict__ y) {
    __shared__ float w1t[HID * KP];  // [j][k]

    const int tid = threadIdx.x;

    // Stage w1 transposed + zero-pad k in [KF, KP)
    for (int k0 = tid; k0 < KP; k0 += 1024) {
        if (k0 < KF) {
            const float4* w4 = (const float4*)(w1 + k0 * HID);
            const float4 a = w4[0], b = w4[1], c = w4[2], d = w4[3];
            w1t[ 0*KP+k0]=a.x; w1t[ 1*KP+k0]=a.y; w1t[ 2*KP+k0]=a.z; w1t[ 3*KP+k0]=a.w;
            w1t[ 4*KP+k0]=b.x; w1t[ 5*KP+k0]=b.y; w1t[ 6*KP+k0]=b.z; w1t[ 7*KP+k0]=b.w;
            w1t[ 8*KP+k0]=c.x; w1t[ 9*KP+k0]=c.y; w1t[10*KP+k0]=c.z; w1t[11*KP+k0]=c.w;
            w1t[12*KP+k0]=d.x; w1t[13*KP+k0]=d.y; w1t[14*KP+k0]=d.z; w1t[15*KP+k0]=d.w;
        } else {
            #pragma unroll
            for (int j = 0; j < HID; ++j) w1t[j * KP + k0] = 0.f;
        }
    }
    __syncthreads();

    const int lane = tid & 63;
    const int m    = lane & 31;          // position within half-wave
    const int h    = lane >> 5;          // which j-half (0: j<8, 1: j>=8)
    const int wid  = blockIdx.x * 16 + (tid >> 6);
    const float* wbase = w1t + h * 8 * KP;   // this half's 8 rows of W1^T

    // element kept by lane m after the 3 halving steps: bitrev3(m&7)
    const int jout = h * 8 + (((m & 1) << 2) | (m & 2) | ((m & 4) >> 2));

    // contiguous, balanced group range for this wave
    const int g0 = (int)(((long long)wid       * NGRP) >> 12);
    const int g1 = (int)(((long long)(wid + 1) * NGRP) >> 12);

    for (int g = g0; g < g1; ++g) {
        const int base = g * ROWS;
        const float* px = x + (size_t)base * KF;

        float acc[ROWS][8];
        #pragma unroll
        for (int r = 0; r < ROWS; ++r)
            #pragma unroll
            for (int q = 0; q < 8; ++q) acc[r][q] = 0.f;

        float xa[ROWS], xb[ROWS];

        auto ld = [&](float* dst, int it) {
            const int k = m + it * 32;
            #pragma unroll
            for (int r = 0; r < ROWS; ++r)
                dst[r] = (k < KF) ? px[(size_t)r * KF + k] : 0.f;
        };
        auto fmab = [&](const float* xv, int it) {
            const int k = m + it * 32;
            #pragma unroll
            for (int q = 0; q < 8; ++q) {
                const float wv = wbase[q * KP + k];
                #pragma unroll
                for (int r = 0; r < ROWS; ++r) acc[r][q] += xv[r] * wv;
            }
        };

        ld(xa, 0);
        ld(xb, 1);
        for (int it = 0; it < NITK - 2; it += 2) {
            fmab(xa, it);     ld(xa, it + 2);   // loads for it+2 fly during fmab(xb)
            fmab(xb, it + 1); ld(xb, it + 3);   // (it+3 may be fully predicated off)
        }
        fmab(xa, NITK - 1);   // it=44 (NITK odd: xa carries the last chunk)

        // Reduce within each 32-lane half: 3 halving steps (8->1) + xor 8,16
        #pragma unroll
        for (int r = 0; r < ROWS; ++r) {
            float v[8];
            #pragma unroll
            for (int q = 0; q < 8; ++q) v[q] = acc[r][q];
            #pragma unroll
            for (int s = 0; s < 3; ++s) {
                const int d    = 1 << s;
                const int half = 4 >> s;
                const int sel  = (m >> s) & 1;
                #pragma unroll
                for (int q2 = 0; q2 < half; ++q2) {
                    const float send = sel ? v[q2] : v[q2 + half];
                    const float keep = sel ? v[q2 + half] : v[q2];
                    v[q2] = keep + __shfl_xor(send, d);
                }
            }
            float t = v[0];
            t += __shfl_xor(t, 8);
            t += __shfl_xor(t, 16);   // no xor 32: halves hold different j's
            if (m < 8) y[(size_t)(base + r) * HID + jout] = t;
        }
    }
}

// ---------------------------------------------------------------------------
// Kernel B: zero the aggregation buffer
// ---------------------------------------------------------------------------
__global__ __launch_bounds__(256) void zero_agg(float4* __restrict__ agg4) {
    const int i = blockIdx.x * 256 + threadIdx.x;
    if (i < NNODES * HID / 4) agg4[i] = make_float4(0.f, 0.f, 0.f, 0.f);
}

// ---------------------------------------------------------------------------
// Kernel C: agg[dst] += y[src]  (thread per (edge, j))
// ---------------------------------------------------------------------------
__global__ __launch_bounds__(256) void scatter_add(const int* __restrict__ ei,
                                                   const float* __restrict__ y,
                                                   float* __restrict__ agg) {
    const int t = blockIdx.x * 256 + threadIdx.x;
    const int e = t >> 4;
    const int j = t & 15;
    if (e < NEDGES) {
        const int s = ei[e];           // src
        const int d = ei[NEDGES + e];  // dst
        atomicAdd(agg + d * HID + j, y[s * HID + j]);
    }
}

// ---------------------------------------------------------------------------
// Kernel D: out = sigmoid(relu((1+eps)*y + agg + b1) @ w2 + b2)
// ---------------------------------------------------------------------------
__global__ __launch_bounds__(256) void mlp_tail(const float* __restrict__ y,
                                                const float* __restrict__ agg,
                                                const float* __restrict__ b1,
                                                const float* __restrict__ w2,
                                                const float* __restrict__ b2,
                                                const float* __restrict__ epsp,
                                                float* __restrict__ out) {
    __shared__ float sw2[HID * NC];
    __shared__ float sb1[HID];
    __shared__ float sb2[NC];
    __shared__ float seps;

    const int t = threadIdx.x;
    if (t < HID * NC) sw2[t] = w2[t];
    if (t < HID)      sb1[t] = b1[t];
    if (t < NC)       sb2[t] = b2[t];
    if (t == 0)       seps = epsp[0];
    __syncthreads();

    const int i = blockIdx.x * 256 + t;
    if (i >= NNODES) return;

    const float co = 1.f + seps;
    const float4* y4 = (const float4*)(y + i * HID);
    const float4* a4 = (const float4*)(agg + i * HID);

    float h[HID];
    #pragma unroll
    for (int q = 0; q < 4; ++q) {
        const float4 yv = y4[q];
        const float4 av = a4[q];
        h[q * 4 + 0] = fmaxf(co * yv.x + av.x + sb1[q * 4 + 0], 0.f);
        h[q * 4 + 1] = fmaxf(co * yv.y + av.y + sb1[q * 4 + 1], 0.f);
        h[q * 4 + 2] = fmaxf(co * yv.z + av.z + sb1[q * 4 + 2], 0.f);
        h[q * 4 + 3] = fmaxf(co * yv.w + av.w + sb1[q * 4 + 3], 0.f);
    }

    #pragma unroll
    for (int c = 0; c < NC; ++c) {
        float s = sb2[c];
        #pragma unroll
        for (int j = 0; j < HID; ++j) s += h[j] * sw2[j * NC + c];
        out[i * NC + c] = 1.f / (1.f + __expf(-s));
    }
}

// ---------------------------------------------------------------------------
extern "C" void kernel_launch(void* const* d_in, const int* in_sizes, int n_in,
                              void* d_out, int out_size, void* d_ws, size_t ws_size,
                              hipStream_t stream) {
    const float* x   = (const float*)d_in[0];
    const int*   ei  = (const int*)d_in[1];
    const float* w1  = (const float*)d_in[2];
    const float* b1  = (const float*)d_in[3];
    const float* w2  = (const float*)d_in[4];
    const float* b2  = (const float*)d_in[5];
    const float* eps = (const float*)d_in[6];
    float* out = (float*)d_out;

    float* y   = (float*)d_ws;                  // NNODES*HID floats (6.4 MB)
    float* agg = y + (size_t)NNODES * HID;      // NNODES*HID floats (6.4 MB)

    gemm_xw1<<<256, 1024, 0, stream>>>(x, w1, y);
    zero_agg<<<(NNODES * HID / 4 + 255) / 256, 256, 0, stream>>>((float4*)agg);
    scatter_add<<<(NEDGES * 16 + 255) / 256, 256, 0, stream>>>(ei, y, agg);
    mlp_tail<<<(NNODES + 255) / 256, 256, 0, stream>>>(y, agg, b1, w2, b2, eps, out);
}

// Round 5
// 1746.193 us; speedup vs baseline: 2.0883x; 2.0883x over previous
//
#include <hip/hip_runtime.h>

#define NNODES 100000
#define NEDGES 300000
#define KF     1433
#define HID    16
#define NC     7
#define ROWS   4
#define KHLEN  768      // k per half-block (12 iters of 64)
#define NITH   12

// ---------------------------------------------------------------------------
// Kernel A: partial GEMM, K split in two halves across blocks.
// 512 threads (8 waves). blockIdx>>8 selects k-half; 256 blocks per half.
// LDS 48KB (half of W1^T) -> 2 blocks/CU possible if VGPR <= 128.
// acc[4][16] = 64 VGPR + prefetch ~8 + addressing => ~100 total.
// 1024-thread blocks are POISON on this toolchain (rounds 2-4: allocator pins
// VGPR_Count=64 regardless of need -> scratch spill -> 7-9 GB HBM traffic).
// 512-thread blocks with this exact lambda/prefetch pattern are proven (rd 1).
// ---------------------------------------------------------------------------
__global__ __launch_bounds__(512) void gemm_xw1_split(const float* __restrict__ x,
                                                      const float* __restrict__ w1,
                                                      float* __restrict__ y0,
                                                      float* __restrict__ y1) {
    __shared__ float wt[HID * KHLEN];  // [j][k_local], 48 KB

    const int khalf = blockIdx.x >> 8;      // 0 or 1
    const int bid   = blockIdx.x & 255;
    const int kbase = khalf * KHLEN;
    const int tid   = threadIdx.x;

    // Stage this half of W1^T, zero-padded past KF
    for (int kl = tid; kl < KHLEN; kl += 512) {
        const int k = kbase + kl;
        if (k < KF) {
            const float4* w4 = (const float4*)(w1 + (size_t)k * HID);
            const float4 a = w4[0], b = w4[1], c = w4[2], d = w4[3];
            wt[ 0*KHLEN+kl]=a.x; wt[ 1*KHLEN+kl]=a.y; wt[ 2*KHLEN+kl]=a.z; wt[ 3*KHLEN+kl]=a.w;
            wt[ 4*KHLEN+kl]=b.x; wt[ 5*KHLEN+kl]=b.y; wt[ 6*KHLEN+kl]=b.z; wt[ 7*KHLEN+kl]=b.w;
            wt[ 8*KHLEN+kl]=c.x; wt[ 9*KHLEN+kl]=c.y; wt[10*KHLEN+kl]=c.z; wt[11*KHLEN+kl]=c.w;
            wt[12*KHLEN+kl]=d.x; wt[13*KHLEN+kl]=d.y; wt[14*KHLEN+kl]=d.z; wt[15*KHLEN+kl]=d.w;
        } else {
            #pragma unroll
            for (int j = 0; j < HID; ++j) wt[j * KHLEN + kl] = 0.f;
        }
    }
    __syncthreads();

    const int lane = tid & 63;
    const int wave = tid >> 6;
    float* __restrict__ yout = khalf ? y1 : y0;
    // element kept by lane after the 4 halving steps: bitrev4(lane&15)
    const int jout = ((lane & 1) << 3) | ((lane & 2) << 1) | ((lane & 4) >> 1) | ((lane & 8) >> 3);

    for (int base = bid * 32 + wave * ROWS; base < NNODES; base += 8192) {
        const float* px = x + (size_t)base * KF;

        float acc[ROWS][HID];
        #pragma unroll
        for (int r = 0; r < ROWS; ++r)
            #pragma unroll
            for (int j = 0; j < HID; ++j) acc[r][j] = 0.f;

        float xa[ROWS], xb[ROWS];

        auto ld = [&](float* dst, int it) {
            const int k = kbase + lane + it * 64;
            #pragma unroll
            for (int r = 0; r < ROWS; ++r)
                dst[r] = (k < KF) ? px[(size_t)r * KF + k] : 0.f;
        };
        auto fmab = [&](const float* xv, int it) {
            const int kl = lane + it * 64;
            #pragma unroll
            for (int j = 0; j < HID; ++j) {
                const float wv = wt[j * KHLEN + kl];   // zero past KF
                #pragma unroll
                for (int r = 0; r < ROWS; ++r) acc[r][j] += xv[r] * wv;
            }
        };

        ld(xa, 0);
        ld(xb, 1);
        for (int it = 0; it < NITH - 2; it += 2) {
            fmab(xa, it);     ld(xa, it + 2);
            fmab(xb, it + 1); ld(xb, it + 3);   // reaches it+3 = 11 at it = 8
        }
        fmab(xa, NITH - 2);
        fmab(xb, NITH - 1);

        // Transpose-reduce (proven rounds 2-4): 16 vals x 64 lanes
        #pragma unroll
        for (int r = 0; r < ROWS; ++r) {
            float v[HID];
            #pragma unroll
            for (int j = 0; j < HID; ++j) v[j] = acc[r][j];
            #pragma unroll
            for (int s = 0; s < 4; ++s) {
                const int d    = 1 << s;
                const int half = 8 >> s;
                const int sel  = (lane >> s) & 1;
                #pragma unroll
                for (int m = 0; m < half; ++m) {
                    const float send = sel ? v[m] : v[m + half];
                    const float keep = sel ? v[m + half] : v[m];
                    v[m] = keep + __shfl_xor(send, d);
                }
            }
            float t = v[0];
            t += __shfl_xor(t, 16);
            t += __shfl_xor(t, 32);
            if (lane < HID) yout[(size_t)(base + r) * HID + jout] = t;
        }
    }
}

// ---------------------------------------------------------------------------
// Kernel B: y = y0 + y1 ; agg = (1+eps) * y   (absorbs zero_agg + eps scale)
// ---------------------------------------------------------------------------
__global__ __launch_bounds__(256) void combine(const float4* __restrict__ y0,
                                               const float4* __restrict__ y1,
                                               float4* __restrict__ y,
                                               float4* __restrict__ agg,
                                               const float* __restrict__ epsp) {
    const int i = blockIdx.x * 256 + threadIdx.x;
    if (i < NNODES * HID / 4) {
        const float co = 1.f + epsp[0];
        const float4 a = y0[i], b = y1[i];
        const float4 s = make_float4(a.x + b.x, a.y + b.y, a.z + b.z, a.w + b.w);
        y[i]   = s;
        agg[i] = make_float4(co * s.x, co * s.y, co * s.z, co * s.w);
    }
}

// ---------------------------------------------------------------------------
// Kernel C: agg[dst] += y[src]  (thread per (edge, j))
// ---------------------------------------------------------------------------
__global__ __launch_bounds__(256) void scatter_add(const int* __restrict__ ei,
                                                   const float* __restrict__ y,
                                                   float* __restrict__ agg) {
    const int t = blockIdx.x * 256 + threadIdx.x;
    const int e = t >> 4;
    const int j = t & 15;
    if (e < NEDGES) {
        const int s = ei[e];           // src
        const int d = ei[NEDGES + e];  // dst
        atomicAdd(agg + d * HID + j, y[s * HID + j]);
    }
}

// ---------------------------------------------------------------------------
// Kernel D: out = sigmoid(relu(agg + b1) @ w2 + b2)   (agg already has eps term)
// ---------------------------------------------------------------------------
__global__ __launch_bounds__(256) void mlp_tail(const float* __restrict__ agg,
                                                const float* __restrict__ b1,
                                                const float* __restrict__ w2,
                                                const float* __restrict__ b2,
                                                float* __restrict__ out) {
    __shared__ float sw2[HID * NC];
    __shared__ float sb1[HID];
    __shared__ float sb2[NC];

    const int t = threadIdx.x;
    if (t < HID * NC) sw2[t] = w2[t];
    if (t < HID)      sb1[t] = b1[t];
    if (t < NC)       sb2[t] = b2[t];
    __syncthreads();

    const int i = blockIdx.x * 256 + t;
    if (i >= NNODES) return;

    const float4* a4 = (const float4*)(agg + i * HID);

    float h[HID];
    #pragma unroll
    for (int q = 0; q < 4; ++q) {
        const float4 av = a4[q];
        h[q * 4 + 0] = fmaxf(av.x + sb1[q * 4 + 0], 0.f);
        h[q * 4 + 1] = fmaxf(av.y + sb1[q * 4 + 1], 0.f);
        h[q * 4 + 2] = fmaxf(av.z + sb1[q * 4 + 2], 0.f);
        h[q * 4 + 3] = fmaxf(av.w + sb1[q * 4 + 3], 0.f);
    }

    #pragma unroll
    for (int c = 0; c < NC; ++c) {
        float s = sb2[c];
        #pragma unroll
        for (int j = 0; j < HID; ++j) s += h[j] * sw2[j * NC + c];
        out[i * NC + c] = 1.f / (1.f + __expf(-s));
    }
}

// ---------------------------------------------------------------------------
extern "C" void kernel_launch(void* const* d_in, const int* in_sizes, int n_in,
                              void* d_out, int out_size, void* d_ws, size_t ws_size,
                              hipStream_t stream) {
    const float* x   = (const float*)d_in[0];
    const int*   ei  = (const int*)d_in[1];
    const float* w1  = (const float*)d_in[2];
    const float* b1  = (const float*)d_in[3];
    const float* w2  = (const float*)d_in[4];
    const float* b2  = (const float*)d_in[5];
    const float* eps = (const float*)d_in[6];
    float* out = (float*)d_out;

    const size_t NY = (size_t)NNODES * HID;
    float* y0  = (float*)d_ws;       // 6.4 MB each
    float* y1  = y0 + NY;
    float* y   = y1 + NY;
    float* agg = y + NY;

    gemm_xw1_split<<<512, 512, 0, stream>>>(x, w1, y0, y1);
    combine<<<(NNODES * HID / 4 + 255) / 256, 256, 0, stream>>>(
        (const float4*)y0, (const float4*)y1, (float4*)y, (float4*)agg, eps);
    scatter_add<<<(NEDGES * 16 + 255) / 256, 256, 0, stream>>>(ei, y, agg);
    mlp_tail<<<(NNODES + 255) / 256, 256, 0, stream>>>(agg, b1, w2, b2, out);
}